// Round 10
// baseline (182.834 us; speedup 1.0000x reference)
//
#include <hip/hip_runtime.h>

// Coords2Grid diagnostic round: dual-dispatch A/B with REPS to lift both
// above the 42us poison fills -> both get rocprof counters.
//   B = ablation (cheap val, writes d_ws, REPS=12): structure-only cost.
//   A = full eval (writes d_out, REPS=5): the real kernel, R7 structure.
#define GR    48
#define GR2   (GR * GR)
#define GR3   (GR * GR * GR)
#define NA    800
#define NT    28
#define RESF  0.5f
#define HALF_DIM 11.75f
#define INV_E2 0.13533528323661270f

#define TXC   2
#define TYC   2
#define TZC   16
#define NTX   (GR / TXC)            // 24
#define NTY   (GR / TYC)            // 24
#define NTZ   (GR / TZC)            // 3
#define NBLK  (NTX * NTY * NTZ)     // 1728
#define KB    64                    // atoms per batch
#define KPAD  80                    // ushort row stride (160B, 16B-aligned)

typedef __attribute__((ext_vector_type(8))) short short8;
typedef __attribute__((ext_vector_type(4))) float floatx4;

__device__ inline unsigned short f2bf(float x) {  // RNE float->bf16 (finite, >=0)
    unsigned u = __builtin_bit_cast(unsigned, x);
    u = (u + 0x7FFFu + ((u >> 16) & 1u)) >> 16;
    return (unsigned short)u;
}

template<int REPS, bool FULL>
__global__ __launch_bounds__(256) void c2g_kernel(
    const float* __restrict__ center,
    const float* __restrict__ coords,
    const float* __restrict__ types,
    const float* __restrict__ radii,
    float* __restrict__ out)
{
    __shared__ float4 s_atom[NA];              // xyz + 1/r^2
    __shared__ int    s_ai[NA];
    __shared__ int    s_cnt;
    __shared__ unsigned short s_val[64 * KPAD]; // [cell][atom] bf16
    __shared__ unsigned short s_tT[32 * KPAD];  // [type][atom] bf16
    __shared__ float  s_out[64 * 33];           // [cell][type] padded

    const int tid  = threadIdx.x;
    const int lane = tid & 63;
    const int w    = tid >> 6;
    const int b    = blockIdx.x;
    const int tz   = b % NTZ;
    const int ty   = (b / NTZ) % NTY;
    const int tx   = b / (NTZ * NTY);

    const float ox = center[0] - HALF_DIM;
    const float oy = center[1] - HALF_DIM;
    const float oz = center[2] - HALF_DIM;

    const float bxlo = ox + tx * (TXC * RESF), bxhi = bxlo + (TXC - 1) * RESF;
    const float bylo = oy + ty * (TYC * RESF), byhi = bylo + (TYC - 1) * RESF;
    const float bzlo = oz + tz * (TZC * RESF), bzhi = bzlo + (TZC - 1) * RESF;

    // Lane -> cell within 2x2x16 tile (z fastest).
    const int lzz = lane & 15;
    const int ly2 = (lane >> 4) & 1;
    const int lx2 = lane >> 5;
    const float gx = bxlo + lx2 * RESF;
    const float gy = bylo + ly2 * RESF;
    const float gz = bzlo + lzz * RESF;

    const int lm = lane & 15;     // MFMA row/col within tile
    const int lg = lane >> 4;     // MFMA k-group

    // Type-staging slots: s in {tid, tid+256}; row = s>>3 (atom), q = s&7.
    const int r0 = tid >> 3,         q0 = tid & 7;
    const int r1 = (tid + 256) >> 3, q1 = tid & 7;  // same q, rows 32..63

    for (int rep = 0; rep < REPS; ++rep) {
        __syncthreads();                 // protect s_cnt/s_out reuse across reps
        if (tid == 0) s_cnt = 0;
        __syncthreads();

        // ---- Prefilter: ballot-compacted ----
        for (int a0 = 0; a0 < NA; a0 += 256) {
            int a = a0 + tid;
            bool accept = false;
            float ax = 0.f, ay = 0.f, az = 0.f, r = 1.f;
            if (a < NA) {
                ax = coords[3 * a + 0];
                ay = coords[3 * a + 1];
                az = coords[3 * a + 2];
                r  = radii[a];
                float cut = 1.5f * r;
                float ddx = ax - fminf(fmaxf(ax, bxlo), bxhi);
                float ddy = ay - fminf(fmaxf(ay, bylo), byhi);
                float ddz = az - fminf(fmaxf(az, bzlo), bzhi);
                float d2 = fmaf(ddx, ddx, fmaf(ddy, ddy, ddz * ddz));
                accept = d2 < cut * cut;
            }
            unsigned long long m = __ballot(accept);
            if (m) {
                int base = 0;
                if (lane == 0) base = atomicAdd(&s_cnt, __popcll(m));
                base = __shfl(base, 0);
                if (accept) {
                    int p = base + __popcll(m & ((1ull << lane) - 1ull));
                    s_atom[p] = make_float4(ax, ay, az, 1.0f / (r * r));
                    s_ai[p] = a;
                }
            }
        }
        __syncthreads();
        const int cnt = s_cnt;

        floatx4 acc0 = {0.f, 0.f, 0.f, 0.f};   // types  0..15
        floatx4 acc1 = {0.f, 0.f, 0.f, 0.f};   // types 16..31 (28..31 pad)

        for (int k0 = 0; k0 < cnt; k0 += KB) {
            const int kmax = (cnt - k0 < KB) ? (cnt - k0) : KB;

            // ---- Issue type-row loads early; zero-fill invalid slots ----
            float4 tv0 = make_float4(0.f, 0.f, 0.f, 0.f);
            float4 tv1 = tv0;
            if (q0 < 7 && r0 < kmax)
                tv0 = *(const float4*)(types + s_ai[k0 + r0] * NT + q0 * 4);
            if (q1 < 7 && r1 < kmax)
                tv1 = *(const float4*)(types + s_ai[k0 + r1] * NT + q1 * 4);

            // ---- Stage A: wave w computes+packs val rows [w*16, w*16+16) ----
            unsigned pk[8];
            #pragma unroll
            for (int jj = 0; jj < 8; ++jj) {
                float v[2];
                #pragma unroll
                for (int h = 0; h < 2; ++h) {
                    int row = w * 16 + 2 * jj + h;
                    float vv = 0.0f;
                    if (row < kmax) {                    // wave-uniform
                        float4 at = s_atom[k0 + row];
                        if constexpr (FULL) {
                            float dx = gx - at.x;
                            float dy = gy - at.y;
                            float dz = gz - at.z;
                            float d2 = fmaf(dx, dx, fmaf(dy, dy, dz * dz));
                            float dr2 = d2 * at.w;
                            float g  = __expf(-2.0f * dr2);
                            float dr = sqrtf(dr2);
                            float q  = INV_E2 * fmaf(4.0f, dr2, fmaf(-12.0f, dr, 9.0f));
                            vv = (dr2 < 1.0f) ? g : ((dr2 < 2.25f) ? q : 0.0f);
                        } else {
                            vv = at.x * at.w;            // ablation: keep load live
                        }
                    }
                    v[h] = vv;
                }
                pk[jj] = (unsigned)f2bf(v[0]) | ((unsigned)f2bf(v[1]) << 16);
            }
            *(uint4*)&s_val[lane * KPAD + w * 16]     = *(uint4*)&pk[0];
            *(uint4*)&s_val[lane * KPAD + w * 16 + 8] = *(uint4*)&pk[4];

            // ---- Transposed type write [type][atom]; q==7 zeros rows 28..31 ----
            {
                const float* e0 = &tv0.x;
                const float* e1 = &tv1.x;
                #pragma unroll
                for (int i = 0; i < 4; ++i) {
                    s_tT[(q0 * 4 + i) * KPAD + r0] = f2bf(e0[i]);
                    s_tT[(q1 * 4 + i) * KPAD + r1] = f2bf(e1[i]);
                }
            }
            __syncthreads();

            // ---- Stage B: MFMA — C[cell-tile w][types] += V-tile * T-tile ----
            #pragma unroll
            for (int ks = 0; ks < 2; ++ks) {
                int ko = ks * 32 + lg * 8;
                short8 afr = *(const short8*)&s_val[(w * 16 + lm) * KPAD + ko];
                short8 b0  = *(const short8*)&s_tT[lm * KPAD + ko];
                short8 b1  = *(const short8*)&s_tT[(16 + lm) * KPAD + ko];
                acc0 = __builtin_amdgcn_mfma_f32_16x16x32_bf16(afr, b0, acc0, 0, 0, 0);
                acc1 = __builtin_amdgcn_mfma_f32_16x16x32_bf16(afr, b1, acc1, 0, 0, 0);
            }
            __syncthreads();
        }

        // ---- Epilogue: acc -> LDS -> coalesced stores ----
        #pragma unroll
        for (int r = 0; r < 4; ++r) {
            int cellO = w * 16 + lg * 4 + r;
            s_out[cellO * 33 + lm]      = acc0[r];
            s_out[cellO * 33 + 16 + lm] = acc1[r];
        }
        __syncthreads();

        #pragma unroll
        for (int i = 0; i < 7; ++i) {
            int idx = i * 256 + tid;                 // < 1792 = 28*64
            int t = idx >> 6;
            int c = idx & 63;
            int z = c & 15, y = (c >> 4) & 1, x = c >> 5;
            int gidx = (tx * TXC + x) * GR2 + (ty * TYC + y) * GR + tz * TZC + z;
            out[t * GR3 + gidx] = s_out[c * 33 + t];
        }
        asm volatile("" ::: "memory");   // no cross-rep CSE
    }
}

extern "C" void kernel_launch(void* const* d_in, const int* in_sizes, int n_in,
                              void* d_out, int out_size, void* d_ws, size_t ws_size,
                              hipStream_t stream) {
    const float* center = (const float*)d_in[0];
    const float* coords = (const float*)d_in[1];
    const float* types  = (const float*)d_in[2];
    const float* radii  = (const float*)d_in[3];

    // B: structure-only ablation -> scratch (d_ws is >= out size; poisoned anyway)
    c2g_kernel<12, false><<<dim3(NBLK), dim3(256), 0, stream>>>(
        center, coords, types, radii, (float*)d_ws);
    // A: full kernel -> d_out (validated)
    c2g_kernel<5, true><<<dim3(NBLK), dim3(256), 0, stream>>>(
        center, coords, types, radii, (float*)d_out);
}

// Round 11
// 71.732 us; speedup vs baseline: 2.5489x; 2.5489x over previous
//
#include <hip/hip_runtime.h>

// Coords2Grid: libmolgrid-style density splat via MFMA (R7 structure +
// XOR bank-swizzled LDS staging).
// C[cell][type] = sum_atoms V[cell][atom] * T[atom][type]
// Staging layout: elem (row,k) at row*KPAD + (((k>>3)^((row>>2)&7))<<3) + (k&7)
//   -> b16 scatter writes 2-way (free), b128 ops at their 8-cycle floor.
#define GR    48
#define GR2   (GR * GR)
#define GR3   (GR * GR * GR)
#define NA    800
#define NT    28
#define RESF  0.5f
#define HALF_DIM 11.75f
#define INV_E2 0.13533528323661270f

#define TXC   2
#define TYC   2
#define TZC   16
#define NTX   (GR / TXC)            // 24
#define NTY   (GR / TYC)            // 24
#define NTZ   (GR / TZC)            // 3
#define NBLK  (NTX * NTY * NTZ)     // 1728
#define KB    64                    // atoms per batch
#define KPAD  80                    // ushort row stride (160B, 16B-aligned)

typedef __attribute__((ext_vector_type(8))) short short8;
typedef __attribute__((ext_vector_type(4))) float floatx4;

__device__ inline unsigned short f2bf(float x) {  // RNE float->bf16 (finite, >=0)
    unsigned u = __builtin_bit_cast(unsigned, x);
    u = (u + 0x7FFFu + ((u >> 16) & 1u)) >> 16;
    return (unsigned short)u;
}

__global__ __launch_bounds__(256) void c2g_kernel(
    const float* __restrict__ center,
    const float* __restrict__ coords,
    const float* __restrict__ types,
    const float* __restrict__ radii,
    float* __restrict__ out)
{
    __shared__ float4 s_atom[NA];              // xyz + 1/r^2
    __shared__ int    s_ai[NA];
    __shared__ int    s_cnt;
    __shared__ unsigned short s_val[64 * KPAD]; // [cell][atom] bf16, swizzled
    __shared__ unsigned short s_tT[32 * KPAD];  // [type][atom] bf16, swizzled
    __shared__ float  s_out[64 * 33];           // [cell][type] padded

    const int tid  = threadIdx.x;
    const int lane = tid & 63;
    const int w    = tid >> 6;
    const int b    = blockIdx.x;
    const int tz   = b % NTZ;
    const int ty   = (b / NTZ) % NTY;
    const int tx   = b / (NTZ * NTY);

    const float ox = center[0] - HALF_DIM;
    const float oy = center[1] - HALF_DIM;
    const float oz = center[2] - HALF_DIM;

    const float bxlo = ox + tx * (TXC * RESF), bxhi = bxlo + (TXC - 1) * RESF;
    const float bylo = oy + ty * (TYC * RESF), byhi = bylo + (TYC - 1) * RESF;
    const float bzlo = oz + tz * (TZC * RESF), bzhi = bzlo + (TZC - 1) * RESF;

    // Lane -> cell within 2x2x16 tile (z fastest).
    const int lzz = lane & 15;
    const int ly2 = (lane >> 4) & 1;
    const int lx2 = lane >> 5;
    const float gx = bxlo + lx2 * RESF;
    const float gy = bylo + ly2 * RESF;
    const float gz = bzlo + lzz * RESF;

    const int lm = lane & 15;     // MFMA row/col within tile
    const int lg = lane >> 4;     // MFMA k-group

    // Type-staging slots: s in {tid, tid+256}; row = s>>3 (atom), q = s&7.
    const int r0 = tid >> 3,         q0 = tid & 7;
    const int r1 = (tid + 256) >> 3, q1 = tid & 7;  // same q, rows 32..63

    if (tid == 0) s_cnt = 0;
    __syncthreads();

    // ---- Prefilter: ballot-compacted ----
    for (int a0 = 0; a0 < NA; a0 += 256) {
        int a = a0 + tid;
        bool accept = false;
        float ax = 0.f, ay = 0.f, az = 0.f, r = 1.f;
        if (a < NA) {
            ax = coords[3 * a + 0];
            ay = coords[3 * a + 1];
            az = coords[3 * a + 2];
            r  = radii[a];
            float cut = 1.5f * r;
            float ddx = ax - fminf(fmaxf(ax, bxlo), bxhi);
            float ddy = ay - fminf(fmaxf(ay, bylo), byhi);
            float ddz = az - fminf(fmaxf(az, bzlo), bzhi);
            float d2 = fmaf(ddx, ddx, fmaf(ddy, ddy, ddz * ddz));
            accept = d2 < cut * cut;
        }
        unsigned long long m = __ballot(accept);
        if (m) {
            int base = 0;
            if (lane == 0) base = atomicAdd(&s_cnt, __popcll(m));
            base = __shfl(base, 0);
            if (accept) {
                int p = base + __popcll(m & ((1ull << lane) - 1ull));
                s_atom[p] = make_float4(ax, ay, az, 1.0f / (r * r));
                s_ai[p] = a;
            }
        }
    }
    __syncthreads();
    const int cnt = s_cnt;

    floatx4 acc0 = {0.f, 0.f, 0.f, 0.f};   // types  0..15
    floatx4 acc1 = {0.f, 0.f, 0.f, 0.f};   // types 16..31 (28..31 pad)

    for (int k0 = 0; k0 < cnt; k0 += KB) {
        const int kmax = (cnt - k0 < KB) ? (cnt - k0) : KB;

        // ---- Issue type-row loads early; zero-fill invalid slots ----
        float4 tv0 = make_float4(0.f, 0.f, 0.f, 0.f);
        float4 tv1 = tv0;
        if (q0 < 7 && r0 < kmax)
            tv0 = *(const float4*)(types + s_ai[k0 + r0] * NT + q0 * 4);
        if (q1 < 7 && r1 < kmax)
            tv1 = *(const float4*)(types + s_ai[k0 + r1] * NT + q1 * 4);

        // ---- Stage A: wave w computes+packs val rows [w*16, w*16+16) ----
        unsigned pk[8];
        #pragma unroll
        for (int jj = 0; jj < 8; ++jj) {
            float v[2];
            #pragma unroll
            for (int h = 0; h < 2; ++h) {
                int row = w * 16 + 2 * jj + h;
                float vv = 0.0f;
                if (row < kmax) {                    // wave-uniform
                    float4 at = s_atom[k0 + row];
                    float dx = gx - at.x;
                    float dy = gy - at.y;
                    float dz = gz - at.z;
                    float d2 = fmaf(dx, dx, fmaf(dy, dy, dz * dz));
                    float dr2 = d2 * at.w;
                    float g  = __expf(-2.0f * dr2);
                    float dr = sqrtf(dr2);
                    float q  = INV_E2 * fmaf(4.0f, dr2, fmaf(-12.0f, dr, 9.0f));
                    vv = (dr2 < 1.0f) ? g : ((dr2 < 2.25f) ? q : 0.0f);
                }
                v[h] = vv;
            }
            pk[jj] = (unsigned)f2bf(v[0]) | ((unsigned)f2bf(v[1]) << 16);
        }
        // Swizzled b128 writes: cell=lane, blocks 2w (k 0..7) and 2w+1 (k 8..15).
        {
            const int usw = (lane >> 2) & 7;
            *(uint4*)&s_val[lane * KPAD + (((2 * w)     ^ usw) << 3)] = *(uint4*)&pk[0];
            *(uint4*)&s_val[lane * KPAD + (((2 * w + 1) ^ usw) << 3)] = *(uint4*)&pk[4];
        }

        // ---- Transposed type write [type][atom], swizzled; q==7 zeros 28..31 ----
        {
            const float* e0 = &tv0.x;
            const float* e1 = &tv1.x;
            const int sw0 = (r0 >> 3) ^ q0;   // (t>>2)&7 == q0 for t=q0*4+i
            const int sw1 = (r1 >> 3) ^ q1;
            #pragma unroll
            for (int i = 0; i < 4; ++i) {
                s_tT[(q0 * 4 + i) * KPAD + (sw0 << 3) + (r0 & 7)] = f2bf(e0[i]);
                s_tT[(q1 * 4 + i) * KPAD + (sw1 << 3) + (r1 & 7)] = f2bf(e1[i]);
            }
        }
        __syncthreads();

        // ---- Stage B: MFMA — C[cell-tile w][types] += V-tile * T-tile ----
        {
            const int uswA = ((w * 16 + lm) >> 2) & 7;  // s_val row swizzle
            const int uswB0 = lm >> 2;                  // s_tT row t=lm
            const int uswB1 = (4 + (lm >> 2)) & 7;      // s_tT row t=16+lm
            #pragma unroll
            for (int ks = 0; ks < 2; ++ks) {
                const int blk = ks * 4 + lg;
                short8 afr = *(const short8*)&s_val[(w * 16 + lm) * KPAD + ((blk ^ uswA) << 3)];
                short8 b0  = *(const short8*)&s_tT[lm * KPAD + ((blk ^ uswB0) << 3)];
                short8 b1  = *(const short8*)&s_tT[(16 + lm) * KPAD + ((blk ^ uswB1) << 3)];
                acc0 = __builtin_amdgcn_mfma_f32_16x16x32_bf16(afr, b0, acc0, 0, 0, 0);
                acc1 = __builtin_amdgcn_mfma_f32_16x16x32_bf16(afr, b1, acc1, 0, 0, 0);
            }
        }
        __syncthreads();
    }

    // ---- Epilogue: acc -> LDS -> coalesced stores ----
    #pragma unroll
    for (int r = 0; r < 4; ++r) {
        int cellO = w * 16 + lg * 4 + r;
        s_out[cellO * 33 + lm]      = acc0[r];
        s_out[cellO * 33 + 16 + lm] = acc1[r];
    }
    __syncthreads();

    #pragma unroll
    for (int i = 0; i < 7; ++i) {
        int idx = i * 256 + tid;                 // < 1792 = 28*64
        int t = idx >> 6;
        int c = idx & 63;
        int z = c & 15, y = (c >> 4) & 1, x = c >> 5;
        int gidx = (tx * TXC + x) * GR2 + (ty * TYC + y) * GR + tz * TZC + z;
        out[t * GR3 + gidx] = s_out[c * 33 + t];
    }
}

extern "C" void kernel_launch(void* const* d_in, const int* in_sizes, int n_in,
                              void* d_out, int out_size, void* d_ws, size_t ws_size,
                              hipStream_t stream) {
    const float* center = (const float*)d_in[0];
    const float* coords = (const float*)d_in[1];
    const float* types  = (const float*)d_in[2];
    const float* radii  = (const float*)d_in[3];
    float* out = (float*)d_out;

    c2g_kernel<<<dim3(NBLK), dim3(256), 0, stream>>>(center, coords, types, radii, out);
}

// Round 12
// 71.104 us; speedup vs baseline: 2.5714x; 1.0088x over previous
//
#include <hip/hip_runtime.h>

// Coords2Grid: libmolgrid-style density splat via MFMA.
// R11 + (a) LDS-staged coords/radii for the prefilter (kills global-load
// latency rounds), (b) s_out aliased onto dead s_atom (LDS 39.9->31.4 KB,
// 4->5 blocks/CU). Math and staging layouts identical to R11.
#define GR    48
#define GR2   (GR * GR)
#define GR3   (GR * GR * GR)
#define NA    800
#define NT    28
#define RESF  0.5f
#define HALF_DIM 11.75f
#define INV_E2 0.13533528323661270f

#define TXC   2
#define TYC   2
#define TZC   16
#define NTX   (GR / TXC)            // 24
#define NTY   (GR / TYC)            // 24
#define NTZ   (GR / TZC)            // 3
#define NBLK  (NTX * NTY * NTZ)     // 1728
#define KB    64                    // atoms per batch
#define KPAD  80                    // ushort row stride (160B, 16B-aligned)

// smem carve-out (bytes)
#define OFF_ATOM 0                  // float4[800]   12800
#define OFF_AI   12800              // int[800]       3200
#define OFF_VAL  16000              // ushort[64*80] 10240
#define OFF_TT   26240              // ushort[32*80]  5120
#define SMEM_SZ  31360
// aliases: s_out float[64*33] @ 0 (s_atom dead by epilogue)
//          s_raw float[3200]  @ 16000 (s_val/s_tT dead during prefilter)

typedef __attribute__((ext_vector_type(8))) short short8;
typedef __attribute__((ext_vector_type(4))) float floatx4;

__device__ inline unsigned short f2bf(float x) {  // RNE float->bf16 (finite, >=0)
    unsigned u = __builtin_bit_cast(unsigned, x);
    u = (u + 0x7FFFu + ((u >> 16) & 1u)) >> 16;
    return (unsigned short)u;
}

__global__ __launch_bounds__(256) void c2g_kernel(
    const float* __restrict__ center,
    const float* __restrict__ coords,
    const float* __restrict__ types,
    const float* __restrict__ radii,
    float* __restrict__ out)
{
    __shared__ __align__(16) unsigned char smem[SMEM_SZ];
    float4*         s_atom = (float4*)(smem + OFF_ATOM);
    int*            s_ai   = (int*)(smem + OFF_AI);
    unsigned short* s_val  = (unsigned short*)(smem + OFF_VAL);
    unsigned short* s_tT   = (unsigned short*)(smem + OFF_TT);
    float*          s_out  = (float*)(smem + OFF_ATOM);   // alias
    float*          s_raw  = (float*)(smem + OFF_VAL);    // alias
    __shared__ int s_cnt;

    const int tid  = threadIdx.x;
    const int lane = tid & 63;
    const int w    = tid >> 6;
    const int b    = blockIdx.x;
    const int tz   = b % NTZ;
    const int ty   = (b / NTZ) % NTY;
    const int tx   = b / (NTZ * NTY);

    const float ox = center[0] - HALF_DIM;
    const float oy = center[1] - HALF_DIM;
    const float oz = center[2] - HALF_DIM;

    const float bxlo = ox + tx * (TXC * RESF), bxhi = bxlo + (TXC - 1) * RESF;
    const float bylo = oy + ty * (TYC * RESF), byhi = bylo + (TYC - 1) * RESF;
    const float bzlo = oz + tz * (TZC * RESF), bzhi = bzlo + (TZC - 1) * RESF;

    // Lane -> cell within 2x2x16 tile (z fastest).
    const int lzz = lane & 15;
    const int ly2 = (lane >> 4) & 1;
    const int lx2 = lane >> 5;
    const float gx = bxlo + lx2 * RESF;
    const float gy = bylo + ly2 * RESF;
    const float gz = bzlo + lzz * RESF;

    const int lm = lane & 15;     // MFMA row/col within tile
    const int lg = lane >> 4;     // MFMA k-group

    // Type-staging slots: s in {tid, tid+256}; row = s>>3 (atom), q = s&7.
    const int r0 = tid >> 3,         q0 = tid & 7;
    const int r1 = (tid + 256) >> 3, q1 = tid & 7;  // same q, rows 32..63

    if (tid == 0) s_cnt = 0;

    // ---- Stage raw coords+radii into LDS (coalesced float4) ----
    {
        const float4* cin = (const float4*)coords;           // 600 float4
        const float4* rin = (const float4*)radii;            // 200 float4
        float4* rawc = (float4*)s_raw;
        float4* rawr = (float4*)(s_raw + 2400);
        #pragma unroll
        for (int i = 0; i < 3; ++i) {
            int idx = i * 256 + tid;
            if (idx < 600) rawc[idx] = cin[idx];
        }
        if (tid < 200) rawr[tid] = rin[tid];
    }
    __syncthreads();

    // ---- Prefilter (from LDS): ballot-compacted ----
    for (int a0 = 0; a0 < NA; a0 += 256) {
        int a = a0 + tid;
        bool accept = false;
        float ax = 0.f, ay = 0.f, az = 0.f, r = 1.f;
        if (a < NA) {
            ax = s_raw[3 * a + 0];
            ay = s_raw[3 * a + 1];
            az = s_raw[3 * a + 2];
            r  = s_raw[2400 + a];
            float cut = 1.5f * r;
            float ddx = ax - fminf(fmaxf(ax, bxlo), bxhi);
            float ddy = ay - fminf(fmaxf(ay, bylo), byhi);
            float ddz = az - fminf(fmaxf(az, bzlo), bzhi);
            float d2 = fmaf(ddx, ddx, fmaf(ddy, ddy, ddz * ddz));
            accept = d2 < cut * cut;
        }
        unsigned long long m = __ballot(accept);
        if (m) {
            int base = 0;
            if (lane == 0) base = atomicAdd(&s_cnt, __popcll(m));
            base = __shfl(base, 0);
            if (accept) {
                int p = base + __popcll(m & ((1ull << lane) - 1ull));
                s_atom[p] = make_float4(ax, ay, az, 1.0f / (r * r));
                s_ai[p] = a;
            }
        }
    }
    __syncthreads();
    const int cnt = s_cnt;

    floatx4 acc0 = {0.f, 0.f, 0.f, 0.f};   // types  0..15
    floatx4 acc1 = {0.f, 0.f, 0.f, 0.f};   // types 16..31 (28..31 pad)

    for (int k0 = 0; k0 < cnt; k0 += KB) {
        const int kmax = (cnt - k0 < KB) ? (cnt - k0) : KB;

        // ---- Issue type-row loads early; zero-fill invalid slots ----
        float4 tv0 = make_float4(0.f, 0.f, 0.f, 0.f);
        float4 tv1 = tv0;
        if (q0 < 7 && r0 < kmax)
            tv0 = *(const float4*)(types + s_ai[k0 + r0] * NT + q0 * 4);
        if (q1 < 7 && r1 < kmax)
            tv1 = *(const float4*)(types + s_ai[k0 + r1] * NT + q1 * 4);

        // ---- Stage A: wave w computes+packs val rows [w*16, w*16+16) ----
        unsigned pk[8];
        #pragma unroll
        for (int jj = 0; jj < 8; ++jj) {
            float v[2];
            #pragma unroll
            for (int h = 0; h < 2; ++h) {
                int row = w * 16 + 2 * jj + h;
                float vv = 0.0f;
                if (row < kmax) {                    // wave-uniform
                    float4 at = s_atom[k0 + row];
                    float dx = gx - at.x;
                    float dy = gy - at.y;
                    float dz = gz - at.z;
                    float d2 = fmaf(dx, dx, fmaf(dy, dy, dz * dz));
                    float dr2 = d2 * at.w;
                    float g  = __expf(-2.0f * dr2);
                    float dr = sqrtf(dr2);
                    float q  = INV_E2 * fmaf(4.0f, dr2, fmaf(-12.0f, dr, 9.0f));
                    vv = (dr2 < 1.0f) ? g : ((dr2 < 2.25f) ? q : 0.0f);
                }
                v[h] = vv;
            }
            pk[jj] = (unsigned)f2bf(v[0]) | ((unsigned)f2bf(v[1]) << 16);
        }
        // Swizzled b128 writes: cell=lane, blocks 2w (k 0..7) and 2w+1 (k 8..15).
        {
            const int usw = (lane >> 2) & 7;
            *(uint4*)&s_val[lane * KPAD + (((2 * w)     ^ usw) << 3)] = *(uint4*)&pk[0];
            *(uint4*)&s_val[lane * KPAD + (((2 * w + 1) ^ usw) << 3)] = *(uint4*)&pk[4];
        }

        // ---- Transposed type write [type][atom], swizzled; q==7 zeros 28..31 ----
        {
            const float* e0 = &tv0.x;
            const float* e1 = &tv1.x;
            const int sw0 = (r0 >> 3) ^ q0;
            const int sw1 = (r1 >> 3) ^ q1;
            #pragma unroll
            for (int i = 0; i < 4; ++i) {
                s_tT[(q0 * 4 + i) * KPAD + (sw0 << 3) + (r0 & 7)] = f2bf(e0[i]);
                s_tT[(q1 * 4 + i) * KPAD + (sw1 << 3) + (r1 & 7)] = f2bf(e1[i]);
            }
        }
        __syncthreads();

        // ---- Stage B: MFMA — C[cell-tile w][types] += V-tile * T-tile ----
        {
            const int uswA = ((w * 16 + lm) >> 2) & 7;  // s_val row swizzle
            const int uswB0 = lm >> 2;                  // s_tT row t=lm
            const int uswB1 = (4 + (lm >> 2)) & 7;      // s_tT row t=16+lm
            #pragma unroll
            for (int ks = 0; ks < 2; ++ks) {
                const int blk = ks * 4 + lg;
                short8 afr = *(const short8*)&s_val[(w * 16 + lm) * KPAD + ((blk ^ uswA) << 3)];
                short8 b0  = *(const short8*)&s_tT[lm * KPAD + ((blk ^ uswB0) << 3)];
                short8 b1  = *(const short8*)&s_tT[(16 + lm) * KPAD + ((blk ^ uswB1) << 3)];
                acc0 = __builtin_amdgcn_mfma_f32_16x16x32_bf16(afr, b0, acc0, 0, 0, 0);
                acc1 = __builtin_amdgcn_mfma_f32_16x16x32_bf16(afr, b1, acc1, 0, 0, 0);
            }
        }
        __syncthreads();
    }

    // ---- Epilogue: acc -> s_out (aliases dead s_atom) -> coalesced stores ----
    #pragma unroll
    for (int r = 0; r < 4; ++r) {
        int cellO = w * 16 + lg * 4 + r;
        s_out[cellO * 33 + lm]      = acc0[r];
        s_out[cellO * 33 + 16 + lm] = acc1[r];
    }
    __syncthreads();

    #pragma unroll
    for (int i = 0; i < 7; ++i) {
        int idx = i * 256 + tid;                 // < 1792 = 28*64
        int t = idx >> 6;
        int c = idx & 63;
        int z = c & 15, y = (c >> 4) & 1, x = c >> 5;
        int gidx = (tx * TXC + x) * GR2 + (ty * TYC + y) * GR + tz * TZC + z;
        out[t * GR3 + gidx] = s_out[c * 33 + t];
    }
}

extern "C" void kernel_launch(void* const* d_in, const int* in_sizes, int n_in,
                              void* d_out, int out_size, void* d_ws, size_t ws_size,
                              hipStream_t stream) {
    const float* center = (const float*)d_in[0];
    const float* coords = (const float*)d_in[1];
    const float* types  = (const float*)d_in[2];
    const float* radii  = (const float*)d_in[3];
    float* out = (float*)d_out;

    c2g_kernel<<<dim3(NBLK), dim3(256), 0, stream>>>(center, coords, types, radii, out);
}